// Round 12
// baseline (20.161 us; speedup 1.0000x reference)
//
#include <hip/hip_runtime.h>
#include <hip/hip_bf16.h>

// Shapes: x,gn (8,128,64) f32; fb (1,128,32768) f32; resonance (64,128) f32.
// out (8,1,32768) f32.
// r[b,c,f] = sum_rr softmax(x+gn)[b,c,rr] * res[rr,f]
// out[b,s] = (1/128) * sum_c lerp(r[b,c,:], s) * fb[c,s]
//
// R12 = R6 (best so far, 17.9us) + ONE change: kA prefetches fb into L2/L3.
// Rationale: every timed replay follows a 268MB d_ws poison fill that evicts
// fb from all caches; kB then streams 16.8MB of COLD fb. kA's blocks are
// latency-bound (shfl chains) with idle VMEM pipes -- each of the 1024 kA
// blocks touches a disjoint 16KB fb slice (16 float4/thread), consumed only
// by a dead asm sink so the loads overlap kA's compute and warm L2/L3 for kB.
// Dead ends so far: grid barrier (R4), redundant softmax (R5/R7/R9/R10),
// batch-split (R2), kB-internal reshuffles (R8/R11: all 18-20us).

#define BATCH 8
#define BANDS 128
#define RES 64
#define NF 128
#define NS 32768
#define NBC (BATCH * BANDS)   // 1024
#define SEG 32
#define NBLKB (NS / SEG)      // 1024

// ---------------- Kernel A: softmax + matvec -> rT[f][b*128+c] ----------------
__global__ __launch_bounds__(64) void kA(const float* __restrict__ x,
                                         const float* __restrict__ gn,
                                         const float* __restrict__ res,
                                         const float* __restrict__ fb,
                                         float* __restrict__ rT) {
    const int bc = blockIdx.x;        // b*128 + c, 0..1023
    const int t  = threadIdx.x;       // 0..63 (one full wave)

    // ---- fb warm-up: block bc touches fb[bc*4096 .. bc*4096+4095] ----
    // Issued first (independent), consumed by a dead sink at the end ->
    // overlaps the latency-bound softmax below; fills L2/L3 for kB.
    const float4* __restrict__ fbp = (const float4*)(fb + (size_t)bc * 4096);
    float warm = 0.f;
    #pragma unroll
    for (int j = 0; j < 16; ++j) {
        const float4 p = fbp[t + 64 * j];
        warm += (p.x + p.y) + (p.z + p.w);
    }

    float v = x[bc * RES + t] + gn[bc * RES + t];

    float m = v;
    #pragma unroll
    for (int off = 32; off > 0; off >>= 1)
        m = fmaxf(m, __shfl_xor(m, off));
    const float e = expf(v - m);
    float ssum = e;
    #pragma unroll
    for (int off = 32; off > 0; off >>= 1)
        ssum += __shfl_xor(ssum, off);
    const float g = e / ssum;

    __shared__ float gs[RES];
    gs[t] = g;
    __syncthreads();

    float r0 = 0.f, r1 = 0.f;
    #pragma unroll 8
    for (int rr = 0; rr < RES; ++rr) {
        const float gg = gs[rr];
        r0 = fmaf(gg, res[rr * NF + t], r0);
        r1 = fmaf(gg, res[rr * NF + t + 64], r1);
    }
    rT[t * NBC + bc]        = r0;
    rT[(t + 64) * NBC + bc] = r1;

    asm volatile("" :: "v"(warm));   // keep prefetch loads alive, no store
}

// ---------------- Kernel B: interp + fb dot + band mean ----------------
// Block k: samples [32k, 32k+31], all 8 batches. thread = (b = tid>>5,
// sl = tid&31). floor(pos) block-uniform (crossings at s=256m+127.5 are
// 32-aligned boundaries) -> stage rlo + dd in LDS. Half-waves read identical
// fb bytes (merged); LDS reads are 2-address broadcasts (free).
__global__ __launch_bounds__(256) void kB(const float* __restrict__ fb,
                                          const float* __restrict__ rT,
                                          float* __restrict__ out) {
    const int k   = blockIdx.x;       // 0..1023
    const int tid = threadIdx.x;      // 0..255
    const int b   = tid >> 5;         // 0..7
    const int sl  = tid & 31;         // 0..31
    const int s   = k * SEG + sl;

    __shared__ float rlo_s[NBC];
    __shared__ float dd_s[NBC];

    float pos0 = ((float)(k * SEG) + 0.5f) * (1.0f / 256.0f) - 0.5f;
    pos0 = fminf(fmaxf(pos0, 0.0f), (float)(NF - 1));
    const int lo0 = (int)floorf(pos0);        // block-uniform
    const int f1  = min(lo0 + 1, NF - 1);

    for (int i = tid; i < NBC; i += 256) {
        const float a  = rT[lo0 * NBC + i];
        const float bb = rT[f1  * NBC + i];
        rlo_s[i] = a;
        dd_s[i]  = bb - a;
    }
    __syncthreads();

    float pos = ((float)s + 0.5f) * (1.0f / 256.0f) - 0.5f;
    pos = fminf(fmaxf(pos, 0.0f), (float)(NF - 1));
    const float w = pos - (float)lo0;

    const float* __restrict__ rl = &rlo_s[b * BANDS];
    const float* __restrict__ dp = &dd_s[b * BANDS];

    float acc = 0.f;
    #pragma unroll 8
    for (int c = 0; c < BANDS; c += 4) {
        const float fb0 = fb[(c + 0) * NS + s];
        const float fb1 = fb[(c + 1) * NS + s];
        const float fb2 = fb[(c + 2) * NS + s];
        const float fb3 = fb[(c + 3) * NS + s];
        const float4 rr = *(const float4*)&rl[c];
        const float4 dd = *(const float4*)&dp[c];
        acc = fmaf(fb0, fmaf(w, dd.x, rr.x), acc);
        acc = fmaf(fb1, fmaf(w, dd.y, rr.y), acc);
        acc = fmaf(fb2, fmaf(w, dd.z, rr.z), acc);
        acc = fmaf(fb3, fmaf(w, dd.w, rr.w), acc);
    }

    out[b * NS + s] = acc * (1.0f / (float)BANDS);
}

extern "C" void kernel_launch(void* const* d_in, const int* in_sizes, int n_in,
                              void* d_out, int out_size, void* d_ws, size_t ws_size,
                              hipStream_t stream) {
    const float* x   = (const float*)d_in[0];
    const float* gn  = (const float*)d_in[1];
    const float* fb  = (const float*)d_in[2];
    const float* res = (const float*)d_in[3];
    float* out = (float*)d_out;
    float* rT  = (float*)d_ws;   // NF * NBC floats = 512 KB

    kA<<<NBC, 64, 0, stream>>>(x, gn, res, fb, rT);
    kB<<<NBLKB, 256, 0, stream>>>(fb, rT, out);
}